// Round 8
// baseline (369.996 us; speedup 1.0000x reference)
//
#include <hip/hip_runtime.h>

#define NEG_SLOPE 0.2f

typedef __attribute__((ext_vector_type(8))) short bf16x8;
typedef __attribute__((ext_vector_type(4))) float f32x4;

__device__ __forceinline__ float leaky(float v) {
    return v > 0.0f ? v : NEG_SLOPE * v;
}
__device__ __forceinline__ float elu(float v) {
    return v > 0.0f ? v : (__expf(v) - 1.0f);
}
__device__ __forceinline__ short f2b(float f) {
    return (short)((__float_as_uint(f) + 0x8000u) >> 16);
}
__device__ __forceinline__ float bf2f(unsigned short v) {
    return __uint_as_float(((unsigned)v) << 16);
}

// ===== prep: zero deg + swizzle both weights into MFMA B-frag order =====
// B-frag: lane=(kk>>3)*16+nn, reg=kk&7 per 32x16 (KxN) tile.
__global__ void prep_k(const float* __restrict__ W1, const float* __restrict__ W2,
                       unsigned short* __restrict__ w1s, unsigned short* __restrict__ w2s,
                       int* __restrict__ deg, int N) {
    int i = blockIdx.x * 256 + threadIdx.x;
    if (i < N) deg[i] = 0;
    if (i < 512 * 64) {                       // W1: K=512, N=64
        int k = i >> 6, n = i & 63;
        int kt = k >> 5, kk = k & 31;
        int nt = n >> 4, nn = n & 15;
        int lane = (kk >> 3) * 16 + nn, j = kk & 7;
        w1s[(((size_t)(kt * 4 + nt)) * 64 + lane) * 8 + j] = (unsigned short)f2b(W1[i]);
    } else if (i < 512 * 64 + 64 * 128) {     // W2: K=64, N=128
        int i2 = i - 512 * 64;
        int k = i2 >> 7, n = i2 & 127;
        int kt = k >> 5, kk = k & 31;
        int nt = n >> 4, nn = n & 15;
        int lane = (kk >> 3) * 16 + nn, j = kk & 7;
        w2s[(((size_t)(kt * 8 + nt)) * 64 + lane) * 8 + j] = (unsigned short)f2b(W2[i2]);
    }
}

// ========== GEMM1 (MFMA bf16) + fused attention dots ==========
// h1b[N,64] = bf16(X[N,512] @ W1), S1[n,h], D1[n,h]
__global__ __launch_bounds__(256) void gemm1_k(const float* __restrict__ X,
                                               const unsigned short* __restrict__ Ws,
                                               const float* __restrict__ Asrc,
                                               const float* __restrict__ Adst,
                                               unsigned short* __restrict__ Hb,
                                               float* __restrict__ S,
                                               float* __restrict__ D, int N) {
    const int lane = threadIdx.x & 63;
    const int wave = threadIdx.x >> 6;
    const int m0 = blockIdx.x * 64 + wave * 16;
    const int q = lane >> 4, lc = lane & 15;
    const int arow = m0 + lc;
    const float* xrow = X + (size_t)min(arow, N - 1) * 512 + q * 8;
    const bf16x8* bW = (const bf16x8*)Ws;

    f32x4 acc[4] = {{0.f,0.f,0.f,0.f},{0.f,0.f,0.f,0.f},{0.f,0.f,0.f,0.f},{0.f,0.f,0.f,0.f}};

    for (int kt = 0; kt < 16; ++kt) {
        float4 a0 = *(const float4*)(xrow + kt * 32);
        float4 a1 = *(const float4*)(xrow + kt * 32 + 4);
        bf16x8 af;
        af[0] = f2b(a0.x); af[1] = f2b(a0.y); af[2] = f2b(a0.z); af[3] = f2b(a0.w);
        af[4] = f2b(a1.x); af[5] = f2b(a1.y); af[6] = f2b(a1.z); af[7] = f2b(a1.w);
#pragma unroll
        for (int nt = 0; nt < 4; ++nt) {
            bf16x8 bf = bW[(size_t)(kt * 4 + nt) * 64 + lane];
            acc[nt] = __builtin_amdgcn_mfma_f32_16x16x32_bf16(af, bf, acc[nt], 0, 0, 0);
        }
    }

    // att vectors indexed flat by col (att[h][c] = A[h*8+c] = A[col])
    float asc[4], adc[4];
#pragma unroll
    for (int nt = 0; nt < 4; ++nt) { asc[nt] = Asrc[nt * 16 + lc]; adc[nt] = Adst[nt * 16 + lc]; }

    // C/D: row = m0+q*4+r, col = nt*16+lc; head(col)=2nt+(lc>>3)
#pragma unroll
    for (int r = 0; r < 4; ++r) {
        int row = m0 + q * 4 + r;
        bool ok = row < N;
        if (ok) {
#pragma unroll
            for (int nt = 0; nt < 4; ++nt)
                Hb[(size_t)row * 64 + nt * 16 + lc] = (unsigned short)f2b(acc[nt][r]);
        }
        float ps[4], pd[4];
#pragma unroll
        for (int nt = 0; nt < 4; ++nt) { ps[nt] = acc[nt][r] * asc[nt]; pd[nt] = acc[nt][r] * adc[nt]; }
#pragma unroll
        for (int off = 1; off < 8; off <<= 1) {
#pragma unroll
            for (int nt = 0; nt < 4; ++nt) {
                ps[nt] += __shfl_xor(ps[nt], off);
                pd[nt] += __shfl_xor(pd[nt], off);
            }
        }
        if (ok && !(lc & 7)) {
            int hb = lc >> 3;
#pragma unroll
            for (int nt = 0; nt < 4; ++nt) {
                S[(size_t)row * 8 + nt * 2 + hb] = ps[nt];
                D[(size_t)row * 8 + nt * 2 + hb] = pd[nt];
            }
        }
    }
}

// ========== GEMM2 (MFMA bf16, bf16 A input) + fused attention dots ==========
// h2b[N,128] = bf16(out1b[N,64] @ W2), S2[n], D2[n]
__global__ __launch_bounds__(256) void gemm2_k(const unsigned short* __restrict__ X,
                                               const unsigned short* __restrict__ Ws,
                                               const float* __restrict__ Asrc,
                                               const float* __restrict__ Adst,
                                               unsigned short* __restrict__ Hb,
                                               float* __restrict__ S,
                                               float* __restrict__ D, int N) {
    const int lane = threadIdx.x & 63;
    const int wave = threadIdx.x >> 6;
    const int m0 = blockIdx.x * 64 + wave * 16;
    const int q = lane >> 4, lc = lane & 15;
    const int arow = m0 + lc;
    const unsigned short* xrow = X + (size_t)min(arow, N - 1) * 64 + q * 8;
    const bf16x8* bW = (const bf16x8*)Ws;

    f32x4 acc[8] = {{0.f,0.f,0.f,0.f},{0.f,0.f,0.f,0.f},{0.f,0.f,0.f,0.f},{0.f,0.f,0.f,0.f},
                    {0.f,0.f,0.f,0.f},{0.f,0.f,0.f,0.f},{0.f,0.f,0.f,0.f},{0.f,0.f,0.f,0.f}};

#pragma unroll
    for (int kt = 0; kt < 2; ++kt) {
        bf16x8 af = *(const bf16x8*)(xrow + kt * 32);   // A rows ARE bf16 fragments
#pragma unroll
        for (int nt = 0; nt < 8; ++nt) {
            bf16x8 bf = bW[(size_t)(kt * 8 + nt) * 64 + lane];
            acc[nt] = __builtin_amdgcn_mfma_f32_16x16x32_bf16(af, bf, acc[nt], 0, 0, 0);
        }
    }

    float asc[8], adc[8];
#pragma unroll
    for (int nt = 0; nt < 8; ++nt) { asc[nt] = Asrc[nt * 16 + lc]; adc[nt] = Adst[nt * 16 + lc]; }

#pragma unroll
    for (int r = 0; r < 4; ++r) {
        int row = m0 + q * 4 + r;
        bool ok = row < N;
        if (ok) {
#pragma unroll
            for (int nt = 0; nt < 8; ++nt)
                Hb[(size_t)row * 128 + nt * 16 + lc] = (unsigned short)f2b(acc[nt][r]);
        }
        float ps = 0.f, pd = 0.f;
#pragma unroll
        for (int nt = 0; nt < 8; ++nt) { ps += acc[nt][r] * asc[nt]; pd += acc[nt][r] * adc[nt]; }
#pragma unroll
        for (int off = 1; off < 16; off <<= 1) {
            ps += __shfl_xor(ps, off);
            pd += __shfl_xor(pd, off);
        }
        if (ok && lc == 0) { S[row] = ps; D[row] = pd; }
    }
}

// ======================= CSR build =======================
__device__ __forceinline__ void edge_sd(const int* ei, int E, int e, int& src, int& dst) {
    if (e < E) { src = ei[e]; dst = ei[E + e]; }
    else       { src = dst = e - E; }
}

__global__ void deg_k(const int* __restrict__ ei, int E, int Etot, int* __restrict__ deg) {
    int e = blockIdx.x * blockDim.x + threadIdx.x;
    if (e >= Etot) return;
    int src, dst; edge_sd(ei, E, e, src, dst);
    atomicAdd(&deg[dst], 1);
}

__global__ __launch_bounds__(256) void scanA_k(const int* __restrict__ deg,
                                               int* __restrict__ rowptr,
                                               int* __restrict__ partials, int N) {
    __shared__ int s[256];
    const int t = threadIdx.x;
    const int base = blockIdx.x * 1024;
    int v[4];
    int idx = base + t * 4;
#pragma unroll
    for (int i = 0; i < 4; ++i) v[i] = (idx + i < N) ? deg[idx + i] : 0;
    int sum = v[0] + v[1] + v[2] + v[3];
    s[t] = sum;
    __syncthreads();
    for (int off = 1; off < 256; off <<= 1) {
        int x = (t >= off) ? s[t - off] : 0;
        __syncthreads();
        s[t] += x;
        __syncthreads();
    }
    int run = s[t] - sum;
#pragma unroll
    for (int i = 0; i < 4; ++i) {
        if (idx + i < N) rowptr[idx + i] = run;
        run += v[i];
    }
    if (t == 255) partials[blockIdx.x] = s[255];
}

__global__ __launch_bounds__(256) void scanB_k(const int* __restrict__ partials,
                                               int* __restrict__ poff,
                                               int* __restrict__ rowptr, int nb,
                                               int N, int Etot) {
    __shared__ int s[256];
    const int t = threadIdx.x;
    int v = (t < nb) ? partials[t] : 0;
    s[t] = v;
    __syncthreads();
    for (int off = 1; off < 256; off <<= 1) {
        int x = (t >= off) ? s[t - off] : 0;
        __syncthreads();
        s[t] += x;
        __syncthreads();
    }
    poff[t] = s[t] - v;
    if (t == 0) rowptr[N] = Etot;
}

__global__ void scanC_k(int* __restrict__ rowptr, const int* __restrict__ poff,
                        int* __restrict__ wp, int N) {
    int i = blockIdx.x * blockDim.x + threadIdx.x;
    if (i >= N) return;
    int r = rowptr[i] + poff[i >> 10];
    rowptr[i] = r;
    wp[i] = r;
}

__global__ void scatter_k(const int* __restrict__ ei, int E, int Etot,
                          int* __restrict__ wp, int* __restrict__ srcs) {
    int e = blockIdx.x * blockDim.x + threadIdx.x;
    if (e >= Etot) return;
    int src, dst; edge_sd(ei, E, e, src, dst);
    int pos = atomicAdd(&wp[dst], 1);
    srcs[pos] = src;
}

// ========= conv1 gather: max-only phase1, fused num/den phase2, bf16 out =========
__global__ __launch_bounds__(256) void agg1_csr_k(const int* __restrict__ rowptr,
                                                  const int* __restrict__ srcs,
                                                  const float* __restrict__ S,
                                                  const float* __restrict__ D,
                                                  const unsigned short* __restrict__ Hb,
                                                  const float* __restrict__ bias,
                                                  unsigned short* __restrict__ out, int N) {
    const int wid = (blockIdx.x * 256 + threadIdx.x) >> 6;
    const int lane = threadIdx.x & 63;
    if (wid >= N) return;
    const int beg = rowptr[wid], end = rowptr[wid + 1];
    const int h = lane & 7;     // weight-space head
    const int el = lane >> 3;   // weight-space edge slot
    const float dvh = D[(size_t)wid * 8 + h];

    // phase 1: pure max (no expf)
    float m = -1e30f;
    for (int i = beg + el; i < end; i += 8)
        m = fmaxf(m, leaky(S[(size_t)srcs[i] * 8 + h] + dvh));
#pragma unroll
    for (int off = 8; off < 64; off <<= 1)
        m = fmaxf(m, __shfl_xor(m, off));

    // phase 2: unnormalized numerator (channel space) + denominator (weight space)
    float acc = 0.0f, den = 0.0f;
    for (int base = beg; base < end; base += 8) {
        int i = base + el;
        int src_l = 0; float w_l = 0.0f;
        if (i < end) {
            src_l = srcs[i];
            w_l = __expf(leaky(S[(size_t)src_l * 8 + h] + dvh) - m);
        }
        den += w_l;
#pragma unroll
        for (int j = 0; j < 8; ++j) {
            float w = __shfl(w_l, j * 8 + (lane >> 3));
            int src = __builtin_amdgcn_readfirstlane(__shfl(src_l, j * 8));
            acc += w * bf2f(Hb[(size_t)src * 64 + lane]);
        }
    }
#pragma unroll
    for (int off = 8; off < 64; off <<= 1)
        den += __shfl_xor(den, off);
    // lane (channel c=lane) needs den of head c>>3; lane k<8 holds head k
    float rden = 1.0f / (__shfl(den, lane >> 3) + 1e-16f);
    out[(size_t)wid * 64 + lane] = (unsigned short)f2b(elu(acc * rden + bias[lane]));
}

// ========= conv2 gather: max-only phase1, fused num/den, 8-deep unroll =========
__global__ __launch_bounds__(256) void agg2_csr_k(const int* __restrict__ rowptr,
                                                  const int* __restrict__ srcs,
                                                  const float* __restrict__ S,
                                                  const float* __restrict__ D,
                                                  const unsigned short* __restrict__ Hb,
                                                  const float* __restrict__ bias,
                                                  float* __restrict__ out, int N) {
    const int wid = (blockIdx.x * 256 + threadIdx.x) >> 6;
    const int lane = threadIdx.x & 63;
    if (wid >= N) return;
    const int beg = rowptr[wid], end = rowptr[wid + 1];
    const float dvh = D[wid];
    const int c0 = lane * 2;

    // phase 1: pure max
    float m = -1e30f;
    for (int i = beg + lane; i < end; i += 64)
        m = fmaxf(m, leaky(S[srcs[i]] + dvh));
#pragma unroll
    for (int off = 1; off < 64; off <<= 1)
        m = fmaxf(m, __shfl_xor(m, off));

    // phase 2: 64-edge chunks, 8 predicated loads in flight
    float acc0 = 0.0f, acc1 = 0.0f, den = 0.0f;
    for (int base = beg; base < end; base += 64) {
        int i = base + lane;
        int src_l = 0; float w_l = 0.0f;
        if (i < end) {
            src_l = srcs[i];
            w_l = __expf(leaky(S[src_l] + dvh) - m);
        }
        den += w_l;
        const int cnt = min(64, end - base);
        for (int j0 = 0; j0 < cnt; j0 += 8) {
#pragma unroll
            for (int u = 0; u < 8; ++u) {
                int j = j0 + u;                 // j>=cnt lanes carry w=0, src=0
                float w = __shfl(w_l, j);
                int src = __builtin_amdgcn_readfirstlane(__shfl(src_l, j));
                unsigned p = *(const unsigned*)(Hb + (size_t)src * 128 + c0);
                acc0 += w * __uint_as_float(p << 16);
                acc1 += w * __uint_as_float(p & 0xffff0000u);
            }
        }
    }
#pragma unroll
    for (int off = 1; off < 64; off <<= 1)
        den += __shfl_xor(den, off);
    const float rden = 1.0f / (den + 1e-16f);
    float2 o;
    o.x = elu(acc0 * rden + bias[c0]);
    o.y = elu(acc1 * rden + bias[c0 + 1]);
    *(float2*)(out + (size_t)wid * 128 + c0) = o;
}

extern "C" void kernel_launch(void* const* d_in, const int* in_sizes, int n_in,
                              void* d_out, int out_size, void* d_ws, size_t ws_size,
                              hipStream_t stream) {
    const float* x   = (const float*)d_in[0];
    const int*   ei  = (const int*)d_in[1];
    const float* W1  = (const float*)d_in[2];
    const float* as1 = (const float*)d_in[3];
    const float* ad1 = (const float*)d_in[4];
    const float* b1  = (const float*)d_in[5];
    const float* W2  = (const float*)d_in[6];
    const float* as2 = (const float*)d_in[7];
    const float* ad2 = (const float*)d_in[8];
    const float* b2  = (const float*)d_in[9];

    const int N = in_sizes[0] / 512;
    const int E = in_sizes[1] / 2;
    const int Etot = E + N;
    float* out = (float*)d_out;

    // ---- workspace layout ----
    unsigned short* w1s    = (unsigned short*)d_ws;                     // 512*64 bf16
    unsigned short* w2s    = w1s + 512 * 64;                            // 64*128 bf16
    unsigned short* out1b  = w2s + 64 * 128;                            // N*64 bf16
    unsigned short* h1b    = out1b + (size_t)N * 64;                    // N*64 bf16
    float*          s1     = (float*)(h1b + (size_t)N * 64);            // N*8
    float*          d1     = s1 + (size_t)N * 8;                        // N*8
    unsigned short* h2b    = (unsigned short*)(d1 + (size_t)N * 8);     // N*128 bf16
    float*          s2     = (float*)(h2b + (size_t)N * 128);           // N
    float*          d2     = s2 + N;                                    // N
    int*            rowptr = (int*)(d2 + N);                            // N+1
    int*            srcs   = rowptr + (N + 1);                          // Etot
    // transient CSR scratch aliased into h2b (dead before gemm2 writes it)
    int* deg      = (int*)h2b;         // N
    int* wp       = deg + N;           // N
    int* partials = wp + N;            // 256
    int* poff     = partials + 256;    // 256

    const int B = 256;
    const int nb = (N + 1023) / 1024;
    const int gblk = (N + 63) / 64;
    const int prep_n = (N > 512 * 64 + 64 * 128) ? N : (512 * 64 + 64 * 128);

    prep_k<<<(prep_n + B - 1) / B, B, 0, stream>>>(W1, W2, w1s, w2s, deg, N);
    deg_k<<<(Etot + B - 1) / B, B, 0, stream>>>(ei, E, Etot, deg);
    scanA_k<<<nb, B, 0, stream>>>(deg, rowptr, partials, N);
    scanB_k<<<1, B, 0, stream>>>(partials, poff, rowptr, nb, N, Etot);
    scanC_k<<<(N + B - 1) / B, B, 0, stream>>>(rowptr, poff, wp, N);
    scatter_k<<<(Etot + B - 1) / B, B, 0, stream>>>(ei, E, Etot, wp, srcs);

    gemm1_k<<<gblk, B, 0, stream>>>(x, w1s, as1, ad1, h1b, s1, d1, N);
    agg1_csr_k<<<(N + 3) / 4, B, 0, stream>>>(rowptr, srcs, s1, d1, h1b, b1, out1b, N);

    gemm2_k<<<gblk, B, 0, stream>>>(out1b, w2s, as2, ad2, h2b, s2, d2, N);
    agg2_csr_k<<<(N + 3) / 4, B, 0, stream>>>(rowptr, srcs, s2, d2, h2b, b2, out, N);
}

// Round 9
// 363.901 us; speedup vs baseline: 1.0167x; 1.0167x over previous
//
#include <hip/hip_runtime.h>

#define NEG_SLOPE 0.2f

typedef __attribute__((ext_vector_type(8))) short bf16x8;
typedef __attribute__((ext_vector_type(4))) float f32x4;

__device__ __forceinline__ float leaky(float v) {
    return v > 0.0f ? v : NEG_SLOPE * v;
}
__device__ __forceinline__ float elu(float v) {
    return v > 0.0f ? v : (__expf(v) - 1.0f);
}
__device__ __forceinline__ short f2b(float f) {
    return (short)((__float_as_uint(f) + 0x8000u) >> 16);
}
__device__ __forceinline__ float bf2f(unsigned short v) {
    return __uint_as_float(((unsigned)v) << 16);
}

// ===== prep: zero deg + swizzle both weights into MFMA B-frag order =====
__global__ void prep_k(const float* __restrict__ W1, const float* __restrict__ W2,
                       unsigned short* __restrict__ w1s, unsigned short* __restrict__ w2s,
                       int* __restrict__ deg, int N) {
    int i = blockIdx.x * 256 + threadIdx.x;
    if (i < N) deg[i] = 0;
    if (i < 512 * 64) {                       // W1: K=512, N=64
        int k = i >> 6, n = i & 63;
        int kt = k >> 5, kk = k & 31;
        int nt = n >> 4, nn = n & 15;
        int lane = (kk >> 3) * 16 + nn, j = kk & 7;
        w1s[(((size_t)(kt * 4 + nt)) * 64 + lane) * 8 + j] = (unsigned short)f2b(W1[i]);
    } else if (i < 512 * 64 + 64 * 128) {     // W2: K=64, N=128
        int i2 = i - 512 * 64;
        int k = i2 >> 7, n = i2 & 127;
        int kt = k >> 5, kk = k & 31;
        int nt = n >> 4, nn = n & 15;
        int lane = (kk >> 3) * 16 + nn, j = kk & 7;
        w2s[(((size_t)(kt * 8 + nt)) * 64 + lane) * 8 + j] = (unsigned short)f2b(W2[i2]);
    }
}

// ========== GEMM1 (MFMA bf16) + fused attention dots ==========
__global__ __launch_bounds__(256) void gemm1_k(const float* __restrict__ X,
                                               const unsigned short* __restrict__ Ws,
                                               const float* __restrict__ Asrc,
                                               const float* __restrict__ Adst,
                                               unsigned short* __restrict__ Hb,
                                               float* __restrict__ S,
                                               float* __restrict__ D, int N) {
    const int lane = threadIdx.x & 63;
    const int wave = threadIdx.x >> 6;
    const int m0 = blockIdx.x * 64 + wave * 16;
    const int q = lane >> 4, lc = lane & 15;
    const int arow = m0 + lc;
    const float* xrow = X + (size_t)min(arow, N - 1) * 512 + q * 8;
    const bf16x8* bW = (const bf16x8*)Ws;

    f32x4 acc[4] = {{0.f,0.f,0.f,0.f},{0.f,0.f,0.f,0.f},{0.f,0.f,0.f,0.f},{0.f,0.f,0.f,0.f}};

    for (int kt = 0; kt < 16; ++kt) {
        float4 a0 = *(const float4*)(xrow + kt * 32);
        float4 a1 = *(const float4*)(xrow + kt * 32 + 4);
        bf16x8 af;
        af[0] = f2b(a0.x); af[1] = f2b(a0.y); af[2] = f2b(a0.z); af[3] = f2b(a0.w);
        af[4] = f2b(a1.x); af[5] = f2b(a1.y); af[6] = f2b(a1.z); af[7] = f2b(a1.w);
#pragma unroll
        for (int nt = 0; nt < 4; ++nt) {
            bf16x8 bf = bW[(size_t)(kt * 4 + nt) * 64 + lane];
            acc[nt] = __builtin_amdgcn_mfma_f32_16x16x32_bf16(af, bf, acc[nt], 0, 0, 0);
        }
    }

    float asc[4], adc[4];
#pragma unroll
    for (int nt = 0; nt < 4; ++nt) { asc[nt] = Asrc[nt * 16 + lc]; adc[nt] = Adst[nt * 16 + lc]; }

#pragma unroll
    for (int r = 0; r < 4; ++r) {
        int row = m0 + q * 4 + r;
        bool ok = row < N;
        if (ok) {
#pragma unroll
            for (int nt = 0; nt < 4; ++nt)
                Hb[(size_t)row * 64 + nt * 16 + lc] = (unsigned short)f2b(acc[nt][r]);
        }
        float ps[4], pd[4];
#pragma unroll
        for (int nt = 0; nt < 4; ++nt) { ps[nt] = acc[nt][r] * asc[nt]; pd[nt] = acc[nt][r] * adc[nt]; }
#pragma unroll
        for (int off = 1; off < 8; off <<= 1) {
#pragma unroll
            for (int nt = 0; nt < 4; ++nt) {
                ps[nt] += __shfl_xor(ps[nt], off);
                pd[nt] += __shfl_xor(pd[nt], off);
            }
        }
        if (ok && !(lc & 7)) {
            int hb = lc >> 3;
#pragma unroll
            for (int nt = 0; nt < 4; ++nt) {
                S[(size_t)row * 8 + nt * 2 + hb] = ps[nt];
                D[(size_t)row * 8 + nt * 2 + hb] = pd[nt];
            }
        }
    }
}

// ========== GEMM2 (MFMA bf16, bf16 A input) + fused attention dots ==========
__global__ __launch_bounds__(256) void gemm2_k(const unsigned short* __restrict__ X,
                                               const unsigned short* __restrict__ Ws,
                                               const float* __restrict__ Asrc,
                                               const float* __restrict__ Adst,
                                               unsigned short* __restrict__ Hb,
                                               float* __restrict__ S,
                                               float* __restrict__ D, int N) {
    const int lane = threadIdx.x & 63;
    const int wave = threadIdx.x >> 6;
    const int m0 = blockIdx.x * 64 + wave * 16;
    const int q = lane >> 4, lc = lane & 15;
    const int arow = m0 + lc;
    const unsigned short* xrow = X + (size_t)min(arow, N - 1) * 64 + q * 8;
    const bf16x8* bW = (const bf16x8*)Ws;

    f32x4 acc[8] = {{0.f,0.f,0.f,0.f},{0.f,0.f,0.f,0.f},{0.f,0.f,0.f,0.f},{0.f,0.f,0.f,0.f},
                    {0.f,0.f,0.f,0.f},{0.f,0.f,0.f,0.f},{0.f,0.f,0.f,0.f},{0.f,0.f,0.f,0.f}};

#pragma unroll
    for (int kt = 0; kt < 2; ++kt) {
        bf16x8 af = *(const bf16x8*)(xrow + kt * 32);   // A rows ARE bf16 fragments
#pragma unroll
        for (int nt = 0; nt < 8; ++nt) {
            bf16x8 bf = bW[(size_t)(kt * 8 + nt) * 64 + lane];
            acc[nt] = __builtin_amdgcn_mfma_f32_16x16x32_bf16(af, bf, acc[nt], 0, 0, 0);
        }
    }

    float asc[8], adc[8];
#pragma unroll
    for (int nt = 0; nt < 8; ++nt) { asc[nt] = Asrc[nt * 16 + lc]; adc[nt] = Adst[nt * 16 + lc]; }

#pragma unroll
    for (int r = 0; r < 4; ++r) {
        int row = m0 + q * 4 + r;
        bool ok = row < N;
        if (ok) {
#pragma unroll
            for (int nt = 0; nt < 8; ++nt)
                Hb[(size_t)row * 128 + nt * 16 + lc] = (unsigned short)f2b(acc[nt][r]);
        }
        float ps = 0.f, pd = 0.f;
#pragma unroll
        for (int nt = 0; nt < 8; ++nt) { ps += acc[nt][r] * asc[nt]; pd += acc[nt][r] * adc[nt]; }
#pragma unroll
        for (int off = 1; off < 16; off <<= 1) {
            ps += __shfl_xor(ps, off);
            pd += __shfl_xor(pd, off);
        }
        if (ok && lc == 0) { S[row] = ps; D[row] = pd; }
    }
}

// ======================= CSR build =======================
// deg over REAL edges only (self-loops added analytically in scanA).
// 8 independent atomic chains per thread for MLP.
__global__ void deg_k(const int* __restrict__ dst, int E, int* __restrict__ deg) {
    int base = (blockIdx.x * blockDim.x + threadIdx.x) * 8;
    if (base + 8 <= E) {
        int4 a = *(const int4*)(dst + base);
        int4 b = *(const int4*)(dst + base + 4);
        atomicAdd(&deg[a.x], 1); atomicAdd(&deg[a.y], 1);
        atomicAdd(&deg[a.z], 1); atomicAdd(&deg[a.w], 1);
        atomicAdd(&deg[b.x], 1); atomicAdd(&deg[b.y], 1);
        atomicAdd(&deg[b.z], 1); atomicAdd(&deg[b.w], 1);
    } else {
        for (int e = base; e < E; ++e) atomicAdd(&deg[dst[e]], 1);
    }
}

__global__ __launch_bounds__(256) void scanA_k(const int* __restrict__ deg,
                                               int* __restrict__ rowptr,
                                               int* __restrict__ partials, int N) {
    __shared__ int s[256];
    const int t = threadIdx.x;
    const int base = blockIdx.x * 1024;
    int v[4];
    int idx = base + t * 4;
#pragma unroll
    for (int i = 0; i < 4; ++i) v[i] = (idx + i < N) ? deg[idx + i] + 1 : 0;  // +1 self-loop
    int sum = v[0] + v[1] + v[2] + v[3];
    s[t] = sum;
    __syncthreads();
    for (int off = 1; off < 256; off <<= 1) {
        int x = (t >= off) ? s[t - off] : 0;
        __syncthreads();
        s[t] += x;
        __syncthreads();
    }
    int run = s[t] - sum;
#pragma unroll
    for (int i = 0; i < 4; ++i) {
        if (idx + i < N) rowptr[idx + i] = run;
        run += v[i];
    }
    if (t == 255) partials[blockIdx.x] = s[255];
}

__global__ __launch_bounds__(256) void scanB_k(const int* __restrict__ partials,
                                               int* __restrict__ poff,
                                               int* __restrict__ rowptr, int nb,
                                               int N, int Etot) {
    __shared__ int s[256];
    const int t = threadIdx.x;
    int v = (t < nb) ? partials[t] : 0;
    s[t] = v;
    __syncthreads();
    for (int off = 1; off < 256; off <<= 1) {
        int x = (t >= off) ? s[t - off] : 0;
        __syncthreads();
        s[t] += x;
        __syncthreads();
    }
    poff[t] = s[t] - v;
    if (t == 0) rowptr[N] = Etot;
}

// finalize rowptr; write self-loop at slot 0 of each row (coalesced); wp starts past it
__global__ void scanC_k(int* __restrict__ rowptr, const int* __restrict__ poff,
                        int* __restrict__ wp, int* __restrict__ srcs, int N) {
    int i = blockIdx.x * blockDim.x + threadIdx.x;
    if (i >= N) return;
    int r = rowptr[i] + poff[i >> 10];
    rowptr[i] = r;
    srcs[r] = i;        // self-loop
    wp[i] = r + 1;
}

// scatter REAL edges; 4 independent atomic->store chains per thread
__global__ void scatter_k(const int* __restrict__ ei, int E,
                          int* __restrict__ wp, int* __restrict__ srcs) {
    int base = (blockIdx.x * blockDim.x + threadIdx.x) * 4;
    if (base + 4 <= E) {
        int4 s = *(const int4*)(ei + base);
        int4 d = *(const int4*)(ei + E + base);
        int p0 = atomicAdd(&wp[d.x], 1);
        int p1 = atomicAdd(&wp[d.y], 1);
        int p2 = atomicAdd(&wp[d.z], 1);
        int p3 = atomicAdd(&wp[d.w], 1);
        srcs[p0] = s.x; srcs[p1] = s.y; srcs[p2] = s.z; srcs[p3] = s.w;
    } else {
        for (int e = base; e < E; ++e) {
            int p = atomicAdd(&wp[ei[E + e]], 1);
            srcs[p] = ei[e];
        }
    }
}

// ========= conv1 gather: max-only phase1, fused num/den phase2, bf16 out =========
__global__ __launch_bounds__(256) void agg1_csr_k(const int* __restrict__ rowptr,
                                                  const int* __restrict__ srcs,
                                                  const float* __restrict__ S,
                                                  const float* __restrict__ D,
                                                  const unsigned short* __restrict__ Hb,
                                                  const float* __restrict__ bias,
                                                  unsigned short* __restrict__ out, int N) {
    const int wid = (blockIdx.x * 256 + threadIdx.x) >> 6;
    const int lane = threadIdx.x & 63;
    if (wid >= N) return;
    const int beg = rowptr[wid], end = rowptr[wid + 1];
    const int h = lane & 7;
    const int el = lane >> 3;
    const float dvh = D[(size_t)wid * 8 + h];

    float m = -1e30f;
    for (int i = beg + el; i < end; i += 8)
        m = fmaxf(m, leaky(S[(size_t)srcs[i] * 8 + h] + dvh));
#pragma unroll
    for (int off = 8; off < 64; off <<= 1)
        m = fmaxf(m, __shfl_xor(m, off));

    float acc = 0.0f, den = 0.0f;
    for (int base = beg; base < end; base += 8) {
        int i = base + el;
        int src_l = 0; float w_l = 0.0f;
        if (i < end) {
            src_l = srcs[i];
            w_l = __expf(leaky(S[(size_t)src_l * 8 + h] + dvh) - m);
        }
        den += w_l;
#pragma unroll
        for (int j = 0; j < 8; ++j) {
            float w = __shfl(w_l, j * 8 + (lane >> 3));
            int src = __builtin_amdgcn_readfirstlane(__shfl(src_l, j * 8));
            acc += w * bf2f(Hb[(size_t)src * 64 + lane]);
        }
    }
#pragma unroll
    for (int off = 8; off < 64; off <<= 1)
        den += __shfl_xor(den, off);
    float rden = 1.0f / (__shfl(den, lane >> 3) + 1e-16f);
    out[(size_t)wid * 64 + lane] = (unsigned short)f2b(elu(acc * rden + bias[lane]));
}

// ========= conv2 gather: max-only phase1, fused num/den, 8-deep unroll =========
__global__ __launch_bounds__(256) void agg2_csr_k(const int* __restrict__ rowptr,
                                                  const int* __restrict__ srcs,
                                                  const float* __restrict__ S,
                                                  const float* __restrict__ D,
                                                  const unsigned short* __restrict__ Hb,
                                                  const float* __restrict__ bias,
                                                  float* __restrict__ out, int N) {
    const int wid = (blockIdx.x * 256 + threadIdx.x) >> 6;
    const int lane = threadIdx.x & 63;
    if (wid >= N) return;
    const int beg = rowptr[wid], end = rowptr[wid + 1];
    const float dvh = D[wid];
    const int c0 = lane * 2;

    float m = -1e30f;
    for (int i = beg + lane; i < end; i += 64)
        m = fmaxf(m, leaky(S[srcs[i]] + dvh));
#pragma unroll
    for (int off = 1; off < 64; off <<= 1)
        m = fmaxf(m, __shfl_xor(m, off));

    float acc0 = 0.0f, acc1 = 0.0f, den = 0.0f;
    for (int base = beg; base < end; base += 64) {
        int i = base + lane;
        int src_l = 0; float w_l = 0.0f;
        if (i < end) {
            src_l = srcs[i];
            w_l = __expf(leaky(S[src_l] + dvh) - m);
        }
        den += w_l;
        const int cnt = min(64, end - base);
        for (int j0 = 0; j0 < cnt; j0 += 8) {
#pragma unroll
            for (int u = 0; u < 8; ++u) {
                int j = j0 + u;
                float w = __shfl(w_l, j);
                int src = __builtin_amdgcn_readfirstlane(__shfl(src_l, j));
                unsigned p = *(const unsigned*)(Hb + (size_t)src * 128 + c0);
                acc0 += w * __uint_as_float(p << 16);
                acc1 += w * __uint_as_float(p & 0xffff0000u);
            }
        }
    }
#pragma unroll
    for (int off = 1; off < 64; off <<= 1)
        den += __shfl_xor(den, off);
    const float rden = 1.0f / (den + 1e-16f);
    float2 o;
    o.x = elu(acc0 * rden + bias[c0]);
    o.y = elu(acc1 * rden + bias[c0 + 1]);
    *(float2*)(out + (size_t)wid * 128 + c0) = o;
}

extern "C" void kernel_launch(void* const* d_in, const int* in_sizes, int n_in,
                              void* d_out, int out_size, void* d_ws, size_t ws_size,
                              hipStream_t stream) {
    const float* x   = (const float*)d_in[0];
    const int*   ei  = (const int*)d_in[1];
    const float* W1  = (const float*)d_in[2];
    const float* as1 = (const float*)d_in[3];
    const float* ad1 = (const float*)d_in[4];
    const float* b1  = (const float*)d_in[5];
    const float* W2  = (const float*)d_in[6];
    const float* as2 = (const float*)d_in[7];
    const float* ad2 = (const float*)d_in[8];
    const float* b2  = (const float*)d_in[9];

    const int N = in_sizes[0] / 512;
    const int E = in_sizes[1] / 2;
    const int Etot = E + N;
    float* out = (float*)d_out;

    // ---- workspace layout ----
    unsigned short* w1s    = (unsigned short*)d_ws;                     // 512*64 bf16
    unsigned short* w2s    = w1s + 512 * 64;                            // 64*128 bf16
    unsigned short* out1b  = w2s + 64 * 128;                            // N*64 bf16
    unsigned short* h1b    = out1b + (size_t)N * 64;                    // N*64 bf16
    float*          s1     = (float*)(h1b + (size_t)N * 64);            // N*8
    float*          d1     = s1 + (size_t)N * 8;                        // N*8
    unsigned short* h2b    = (unsigned short*)(d1 + (size_t)N * 8);     // N*128 bf16
    float*          s2     = (float*)(h2b + (size_t)N * 128);           // N
    float*          d2     = s2 + N;                                    // N
    int*            rowptr = (int*)(d2 + N);                            // N+1
    int*            srcs   = rowptr + (N + 1);                          // Etot
    // transient CSR scratch aliased into h2b (dead before gemm2 writes it)
    int* deg      = (int*)h2b;         // N
    int* wp       = deg + N;           // N
    int* partials = wp + N;            // 256
    int* poff     = partials + 256;    // 256

    const int B = 256;
    const int nb = (N + 1023) / 1024;
    const int gblk = (N + 63) / 64;
    const int prep_n = (N > 512 * 64 + 64 * 128) ? N : (512 * 64 + 64 * 128);

    prep_k<<<(prep_n + B - 1) / B, B, 0, stream>>>(W1, W2, w1s, w2s, deg, N);
    deg_k<<<(E + B * 8 - 1) / (B * 8), B, 0, stream>>>(ei + E, E, deg);
    scanA_k<<<nb, B, 0, stream>>>(deg, rowptr, partials, N);
    scanB_k<<<1, B, 0, stream>>>(partials, poff, rowptr, nb, N, Etot);
    scanC_k<<<(N + B - 1) / B, B, 0, stream>>>(rowptr, poff, wp, srcs, N);
    scatter_k<<<(E + B * 4 - 1) / (B * 4), B, 0, stream>>>(ei, E, wp, srcs);

    gemm1_k<<<gblk, B, 0, stream>>>(x, w1s, as1, ad1, h1b, s1, d1, N);
    agg1_csr_k<<<(N + 3) / 4, B, 0, stream>>>(rowptr, srcs, s1, d1, h1b, b1, out1b, N);

    gemm2_k<<<gblk, B, 0, stream>>>(out1b, w2s, as2, ad2, h2b, s2, d2, N);
    agg2_csr_k<<<(N + 3) / 4, B, 0, stream>>>(rowptr, srcs, s2, d2, h2b, b2, out, N);
}